// Round 1
// 1016.506 us; speedup vs baseline: 1.0737x; 1.0737x over previous
//
#include <hip/hip_runtime.h>
#include <cstdint>
#include <cstddef>

// ---------------------------------------------------------------------------
// GatedGIN forward. Inputs bf16-or-f32 (runtime probe), OUTPUT = FLOAT32.
// Round 12: (1) per-vXCD sub-segmented CSR: hist/scan/scatter use
// deg2[node*8 + (blockIdx&7)] so each XCD appends only into its own 1.6MB
// payload slice (fits its 4MB L2) -> kills the ~8x scatter write
// amplification. scan2 parallelized (800K block-sums). (2) k_mm<1>+k_heads
// fused: head-hidden tile stays in LDS, saves 51.2MB traffic/layer.
// ---------------------------------------------------------------------------

typedef short  v8s __attribute__((ext_vector_type(8)));
typedef float  v4f __attribute__((ext_vector_type(4)));

static __device__ __forceinline__ float bf2f(uint16_t u) {
  return __uint_as_float(((uint32_t)u) << 16);
}
static __device__ __forceinline__ uint16_t f2b(float f) {
  uint32_t x = __float_as_uint(f);
  return (uint16_t)((x + 0x7FFFu + ((x >> 16) & 1u)) >> 16);
}
static __device__ __forceinline__ float sigmoidf_(float v) {
  return 1.f / (1.f + __expf(-v));
}

// ---------------- dtype probe ----------------
__global__ void k_detect(const uint32_t* __restrict__ u, int* __restrict__ flag) {
  int lane = threadIdx.x;  // 64 threads
  uint32_t low = u[lane] & 0xFFFFu;
  uint32_t e = (low >> 7) & 0xFFu;
  bool pass = (e == 0) || (e >= 110 && e <= 141);
  unsigned long long b = __ballot(pass);
  if (lane == 0) *flag = (__popcll(b) >= 32) ? 1 : 0;
}

// ---------------- weight convert: one pass -> f32 arena + bf16 arena -------
struct CvtDesc {
  const void* src[18];
  int off[19];
};

__global__ void k_cvtw(CvtDesc c, float* __restrict__ wbase,
                       uint16_t* __restrict__ wb16,
                       const int* __restrict__ flag, int total) {
  int gid = blockIdx.x * 256 + threadIdx.x;
  if (gid >= total) return;
  int t = 0;
#pragma unroll
  for (int i = 1; i < 18; i++)
    if (gid >= c.off[i]) t = i;
  int local = gid - c.off[t];
  float v;
  if (*flag) v = bf2f(((const uint16_t*)c.src[t])[local]);
  else       v = ((const float*)c.src[t])[local];
  wbase[gid] = v;
  wb16[gid] = f2b(v);
}

__global__ void k_cvt_feat(const void* __restrict__ src, uint16_t* __restrict__ dst,
                           int n, const int* __restrict__ flag) {
  int i = blockIdx.x * 256 + threadIdx.x;
  if (i >= n) return;
  if (*flag) dst[i] = ((const uint16_t*)src)[i];
  else       dst[i] = f2b(((const float*)src)[i]);
}

__global__ void k_zero_i(int* __restrict__ p, int n) {
  int i = blockIdx.x * 256 + threadIdx.x;
  if (i < n) p[i] = 0;
}

__global__ void k_zero_f(float* __restrict__ p, int n) {
  int i = blockIdx.x * 256 + threadIdx.x;
  if (i < n) p[i] = 0.f;
}

// ---------------- weight repack: fragment-major for 16x16x32 MFMA ----------
__global__ void k_pack_mm(const uint16_t* __restrict__ src, uint16_t* __restrict__ dst,
                          int nmat) {
  int id = blockIdx.x * 256 + threadIdx.x;
  if (id >= nmat * 2048) return;
  int mat = id >> 11;
  int rem = id & 2047;
  int blk = rem >> 6, lane = rem & 63;
  int kc = blk >> 3, t = blk & 7;
  int n0 = lane & 15, quad = lane >> 4;
  const uint16_t* s = src + (size_t)mat * 16384 + (size_t)(t * 16 + n0) * 128 + kc * 32 + quad * 8;
  uint16_t* d = dst + (size_t)id * 8;
  *reinterpret_cast<v8s*>(d) = *reinterpret_cast<const v8s*>(s);
}

// GRU layout: blk = (kc*4 + w)*12 + (u*2 + mat)*3 + g  (192 blocks/layer)
__global__ void k_pack_gru(const uint16_t* __restrict__ wih, const uint16_t* __restrict__ whh,
                           uint16_t* __restrict__ dst, int nlayer) {
  int id = blockIdx.x * 256 + threadIdx.x;
  if (id >= nlayer * 192 * 64) return;
  int lane = id & 63;
  int blk = (id >> 6) % 192;
  int layer = (id >> 6) / 192;
  int g = blk % 3;
  int mat = (blk / 3) % 2;
  int u = (blk / 6) % 2;
  int w = (blk / 12) % 4;
  int kc = blk / 48;
  int n0 = lane & 15, quad = lane >> 4;
  const uint16_t* base = (mat == 0 ? wih : whh) + (size_t)layer * 384 * 128;
  const uint16_t* s = base + (size_t)(g * 128 + w * 32 + u * 16 + n0) * 128 + kc * 32 + quad * 8;
  uint16_t* d = dst + ((size_t)layer * 192 + blk) * 512 + (size_t)lane * 8;
  *reinterpret_cast<v8s*>(d) = *reinterpret_cast<const v8s*>(s);
}

// ---------------- CSR build (per-vXCD sub-segmented) ----------------
// deg2/cursor2/rowptr2 indexed by node*8 + vxcd where vxcd = blockIdx&7 of the
// edge-grid. hist and scatter use identical grids so the class of each edge
// matches. Node n's edges end up contiguous in [rowptr2[8n], rowptr2[8n+8]).
__global__ void k_hist(const int* __restrict__ dst, int* __restrict__ deg2, int E) {
  int e = blockIdx.x * 256 + threadIdx.x;
  if (e < E) atomicAdd(&deg2[(size_t)dst[e] * 8 + (blockIdx.x & 7)], 1);
}

__global__ void k_scan1(const int* __restrict__ deg, int* __restrict__ bsum, int n) {
  __shared__ int red[256];
  int t = threadIdx.x;
  int base = blockIdx.x * 1024;
  int s = 0;
#pragma unroll
  for (int i = 0; i < 4; i++) {
    int idx = base + i * 256 + t;
    if (idx < n) s += deg[idx];
  }
  red[t] = s;
  __syncthreads();
  for (int off = 128; off > 0; off >>= 1) {
    if (t < off) red[t] += red[t + off];
    __syncthreads();
  }
  if (t == 0) bsum[blockIdx.x] = red[0];
}

// parallel exclusive scan over up to 1024 block sums (one block, 256 thr x 4)
__global__ void k_scan2(int* bsum, int nb, int* rowptr, int n) {
  __shared__ int red[256];
  int t = threadIdx.x;
  int v[4];
  int s = 0;
#pragma unroll
  for (int i = 0; i < 4; i++) {
    int idx = t * 4 + i;
    v[i] = (idx < nb) ? bsum[idx] : 0;
    s += v[i];
  }
  red[t] = s;
  __syncthreads();
  for (int off = 1; off < 256; off <<= 1) {
    int u = (t >= off) ? red[t - off] : 0;
    __syncthreads();
    red[t] += u;
    __syncthreads();
  }
  int run = red[t] - s;  // exclusive prefix of this thread's chunk
#pragma unroll
  for (int i = 0; i < 4; i++) {
    int idx = t * 4 + i;
    if (idx < nb) { bsum[idx] = run; run += v[i]; }
  }
  if (t == 255) rowptr[n] = red[255];  // == E
}

__global__ void k_scan3(const int* __restrict__ deg, const int* __restrict__ bsum,
                        int* __restrict__ rowptr, int* __restrict__ cursor, int n) {
  __shared__ int lds[256];
  int t = threadIdx.x;
  int base = blockIdx.x * 1024 + t * 4;
  int v0 = 0, v1 = 0, v2 = 0, v3 = 0;
  if (base + 0 < n) v0 = deg[base + 0];
  if (base + 1 < n) v1 = deg[base + 1];
  if (base + 2 < n) v2 = deg[base + 2];
  if (base + 3 < n) v3 = deg[base + 3];
  int s = v0 + v1 + v2 + v3;
  lds[t] = s;
  __syncthreads();
  for (int off = 1; off < 256; off <<= 1) {
    int u = (t >= off) ? lds[t - off] : 0;
    __syncthreads();
    lds[t] += u;
    __syncthreads();
  }
  int run = lds[t] - s + bsum[blockIdx.x];
  if (base + 0 < n) { rowptr[base + 0] = run; cursor[base + 0] = run; run += v0; }
  if (base + 1 < n) { rowptr[base + 1] = run; cursor[base + 1] = run; run += v1; }
  if (base + 2 < n) { rowptr[base + 2] = run; cursor[base + 2] = run; run += v2; }
  if (base + 3 < n) { rowptr[base + 3] = run; cursor[base + 3] = run; run += v3; }
}

// packed edge payload: .x = src node, .y = weight bits (f32)
__global__ void k_scatter(const int* __restrict__ dst, const int* __restrict__ src,
                          const void* __restrict__ w, int* __restrict__ cursor2,
                          uint2* __restrict__ ep, const int* __restrict__ flag, int E) {
  int e = blockIdx.x * 256 + threadIdx.x;
  if (e < E) {
    int d = dst[e];
    int pos = atomicAdd(&cursor2[(size_t)d * 8 + (blockIdx.x & 7)], 1);
    float wv;
    if (*flag) wv = bf2f(((const uint16_t*)w)[e]);
    else       wv = ((const float*)w)[e];
    ep[pos] = make_uint2((uint32_t)src[e], __float_as_uint(wv));
  }
}

// ---------------- SpMM gather: 4 nodes/block, 64 thr/node, unroll 4 --------
__global__ void k_spmm(const uint16_t* __restrict__ x, const int* __restrict__ rowptr2,
                       const uint2* __restrict__ ep, uint16_t* __restrict__ agg, int n) {
  int node = blockIdx.x * 4 + (threadIdx.x >> 6);
  int lane = threadIdx.x & 63;
  if (node >= n) return;
  int p0 = rowptr2[(size_t)node * 8], p1 = rowptr2[(size_t)node * 8 + 8];
  float a0 = 0.f, a1 = 0.f;
  int p = p0;
  for (; p + 3 < p1; p += 4) {
    uint2 e0 = ep[p], e1 = ep[p + 1], e2 = ep[p + 2], e3 = ep[p + 3];
    uint32_t u0 = *reinterpret_cast<const uint32_t*>(x + (size_t)e0.x * 128 + lane * 2);
    uint32_t u1 = *reinterpret_cast<const uint32_t*>(x + (size_t)e1.x * 128 + lane * 2);
    uint32_t u2 = *reinterpret_cast<const uint32_t*>(x + (size_t)e2.x * 128 + lane * 2);
    uint32_t u3 = *reinterpret_cast<const uint32_t*>(x + (size_t)e3.x * 128 + lane * 2);
    float w0 = __uint_as_float(e0.y), w1 = __uint_as_float(e1.y);
    float w2 = __uint_as_float(e2.y), w3 = __uint_as_float(e3.y);
    a0 = fmaf(w0, bf2f((uint16_t)u0), a0);
    a1 = fmaf(w0, bf2f((uint16_t)(u0 >> 16)), a1);
    a0 = fmaf(w1, bf2f((uint16_t)u1), a0);
    a1 = fmaf(w1, bf2f((uint16_t)(u1 >> 16)), a1);
    a0 = fmaf(w2, bf2f((uint16_t)u2), a0);
    a1 = fmaf(w2, bf2f((uint16_t)(u2 >> 16)), a1);
    a0 = fmaf(w3, bf2f((uint16_t)u3), a0);
    a1 = fmaf(w3, bf2f((uint16_t)(u3 >> 16)), a1);
  }
  for (; p < p1; p++) {
    uint2 e0 = ep[p];
    float w0 = __uint_as_float(e0.y);
    uint32_t u0 = *reinterpret_cast<const uint32_t*>(x + (size_t)e0.x * 128 + lane * 2);
    a0 = fmaf(w0, bf2f((uint16_t)u0), a0);
    a1 = fmaf(w0, bf2f((uint16_t)(u0 >> 16)), a1);
  }
  uint32_t packed = (uint32_t)f2b(a0) | ((uint32_t)f2b(a1) << 16);
  *reinterpret_cast<uint32_t*>(agg + (size_t)node * 128 + lane * 2) = packed;
}

// ---------------- MFMA matmul, repacked W, 32 rows/wave ----------
// EPI 1 = relu; EPI 2 = relu + row-norm. Out bf16. Block = 4 waves = 128 rows.
template <int EPI>
__launch_bounds__(256)
__global__ void k_mm(const uint16_t* __restrict__ A, const uint16_t* __restrict__ Wrp,
                     const float* __restrict__ bias, uint16_t* __restrict__ C,
                     int nrows) {
  int wave = threadIdx.x >> 6, lane = threadIdx.x & 63;
  int n0 = lane & 15, quad = lane >> 4;
  int m0 = (blockIdx.x * 4 + wave) * 32;
  int r0 = m0 + n0, r1 = m0 + 16 + n0;
  bool ok0 = r0 < nrows, ok1 = r1 < nrows;
  const v8s z8 = {0, 0, 0, 0, 0, 0, 0, 0};

  v4f acc[2][8];
#pragma unroll
  for (int rt = 0; rt < 2; rt++)
#pragma unroll
    for (int t = 0; t < 8; t++) acc[rt][t] = {0.f, 0.f, 0.f, 0.f};

  const uint16_t* ap0 = A + (size_t)r0 * 128 + quad * 8;
  const uint16_t* ap1 = A + (size_t)r1 * 128 + quad * 8;
#pragma unroll
  for (int kc = 0; kc < 4; kc++) {
    v8s a0 = ok0 ? *reinterpret_cast<const v8s*>(ap0 + kc * 32) : z8;
    v8s a1 = ok1 ? *reinterpret_cast<const v8s*>(ap1 + kc * 32) : z8;
    const uint16_t* wp = Wrp + (size_t)kc * 4096 + (size_t)lane * 8;
#pragma unroll
    for (int t = 0; t < 8; t++) {
      v8s bf = *reinterpret_cast<const v8s*>(wp + t * 512);
      acc[0][t] = __builtin_amdgcn_mfma_f32_16x16x32_bf16(a0, bf, acc[0][t], 0, 0, 0);
      acc[1][t] = __builtin_amdgcn_mfma_f32_16x16x32_bf16(a1, bf, acc[1][t], 0, 0, 0);
    }
  }

#pragma unroll
  for (int rt = 0; rt < 2; rt++) {
    int mb = m0 + rt * 16;
    float vv[8][4];
#pragma unroll
    for (int t = 0; t < 8; t++) {
      float b = bias[t * 16 + n0];
#pragma unroll
      for (int r = 0; r < 4; r++) vv[t][r] = fmaxf(acc[rt][t][r] + b, 0.f);
    }
    if (EPI == 2) {
#pragma unroll
      for (int r = 0; r < 4; r++) {
        float ss = 0.f;
#pragma unroll
        for (int t = 0; t < 8; t++) ss = fmaf(vv[t][r], vv[t][r], ss);
        ss += __shfl_xor(ss, 1);
        ss += __shfl_xor(ss, 2);
        ss += __shfl_xor(ss, 4);
        ss += __shfl_xor(ss, 8);
        float sc = rsqrtf(1.f + ss);
#pragma unroll
        for (int t = 0; t < 8; t++) vv[t][r] *= sc;
      }
    }
#pragma unroll
    for (int r = 0; r < 4; r++) {
      int row = mb + quad * 4 + r;
      if (row >= nrows) continue;
#pragma unroll
      for (int t = 0; t < 8; t++)
        C[(size_t)row * 128 + t * 16 + n0] = f2b(vv[t][r]);
    }
  }
}

// ---------------- fused head-mlp1 + head: hid tile stays in LDS ------------
// Phase 1 = k_mm<1> (hid = relu(x @ hw1^T + hb1)) -> bf16 LDS tile
// (128x130: stride 65 dwords -> 2-way free bank aliasing on row reads).
// Phase 2 = per-row head dot (C outputs) + log_softmax/softmax, FLOAT32 out.
// Accumulation order identical to the old k_heads (sequential fmaf k=0..127).
template <int C>
__launch_bounds__(256)
__global__ void k_mmh(const uint16_t* __restrict__ A, const uint16_t* __restrict__ Wrp,
                      const float* __restrict__ bias,
                      const float* __restrict__ w2, const float* __restrict__ b2,
                      float* __restrict__ out_log, float* __restrict__ out_soft,
                      int nrows) {
  __shared__ uint16_t hl[128][130];
  int wave = threadIdx.x >> 6, lane = threadIdx.x & 63;
  int n0 = lane & 15, quad = lane >> 4;
  int m0 = (blockIdx.x * 4 + wave) * 32;
  int r0 = m0 + n0, r1 = m0 + 16 + n0;
  bool ok0 = r0 < nrows, ok1 = r1 < nrows;
  const v8s z8 = {0, 0, 0, 0, 0, 0, 0, 0};

  v4f acc[2][8];
#pragma unroll
  for (int rt = 0; rt < 2; rt++)
#pragma unroll
    for (int t = 0; t < 8; t++) acc[rt][t] = {0.f, 0.f, 0.f, 0.f};

  const uint16_t* ap0 = A + (size_t)r0 * 128 + quad * 8;
  const uint16_t* ap1 = A + (size_t)r1 * 128 + quad * 8;
#pragma unroll
  for (int kc = 0; kc < 4; kc++) {
    v8s a0 = ok0 ? *reinterpret_cast<const v8s*>(ap0 + kc * 32) : z8;
    v8s a1 = ok1 ? *reinterpret_cast<const v8s*>(ap1 + kc * 32) : z8;
    const uint16_t* wp = Wrp + (size_t)kc * 4096 + (size_t)lane * 8;
#pragma unroll
    for (int t = 0; t < 8; t++) {
      v8s bf = *reinterpret_cast<const v8s*>(wp + t * 512);
      acc[0][t] = __builtin_amdgcn_mfma_f32_16x16x32_bf16(a0, bf, acc[0][t], 0, 0, 0);
      acc[1][t] = __builtin_amdgcn_mfma_f32_16x16x32_bf16(a1, bf, acc[1][t], 0, 0, 0);
    }
  }

  // epilogue: bias + relu -> LDS (OOB rows hold finite junk, never read)
#pragma unroll
  for (int rt = 0; rt < 2; rt++) {
#pragma unroll
    for (int t = 0; t < 8; t++) {
      float b = bias[t * 16 + n0];
#pragma unroll
      for (int r = 0; r < 4; r++) {
        int rl = wave * 32 + rt * 16 + quad * 4 + r;
        hl[rl][t * 16 + n0] = f2b(fmaxf(acc[rt][t][r] + b, 0.f));
      }
    }
  }
  __syncthreads();

  // phase 2: one thread per row
  int tid = threadIdx.x;
  if (tid < 128) {
    int node = blockIdx.x * 128 + tid;
    if (node < nrows) {
      float lg[C];
#pragma unroll
      for (int c = 0; c < C; c++) lg[c] = b2[c];
      for (int k = 0; k < 64; k++) {
        uint32_t u = *reinterpret_cast<const uint32_t*>(&hl[tid][2 * k]);
        float x0 = bf2f((uint16_t)u);
        float x1 = bf2f((uint16_t)(u >> 16));
#pragma unroll
        for (int c = 0; c < C; c++) lg[c] = fmaf(x0, w2[c * 128 + 2 * k], lg[c]);
#pragma unroll
        for (int c = 0; c < C; c++) lg[c] = fmaf(x1, w2[c * 128 + 2 * k + 1], lg[c]);
      }
      float m = lg[0];
#pragma unroll
      for (int c = 1; c < C; c++) m = fmaxf(m, lg[c]);
      float s = 0.f;
      float e[C];
#pragma unroll
      for (int c = 0; c < C; c++) { e[c] = __expf(lg[c] - m); s += e[c]; }
      float ls = __logf(s);
      float inv = 1.f / s;
#pragma unroll
      for (int c = 0; c < C; c++) {
        out_log[(size_t)node * C + c] = lg[c] - m - ls;
        out_soft[(size_t)node * C + c] = e[c] * inv;
      }
    }
  }
}

// ---------------- fused GRU + GIN-mlp1, 32 rows/block ----------------
__launch_bounds__(256)
__global__ void k_grug(const uint16_t* aggio, const uint16_t* __restrict__ xb,
                       const uint16_t* __restrict__ Wrp,
                       const uint16_t* __restrict__ G1rp,
                       const float* __restrict__ bih, const float* __restrict__ bhh,
                       const float* __restrict__ gb1,
                       uint16_t* hidout, int n) {
  __shared__ uint16_t hl[32][136];  // pad 8 bf16 -> 2-way max bank aliasing
  int wave = threadIdx.x >> 6, lane = threadIdx.x & 63;
  int n0 = lane & 15, quad = lane >> 4;
  int m0 = blockIdx.x * 32;
  int r0 = m0 + n0, r1 = m0 + 16 + n0;
  bool ok0 = r0 < n, ok1 = r1 < n;
  const v8s z8 = {0, 0, 0, 0, 0, 0, 0, 0};

  v4f accI[2][2][3], accH[2][2][3];  // [rowtile][u][gate]
#pragma unroll
  for (int rt = 0; rt < 2; rt++)
#pragma unroll
    for (int u = 0; u < 2; u++)
#pragma unroll
      for (int g = 0; g < 3; g++) {
        accI[rt][u][g] = {0.f, 0.f, 0.f, 0.f};
        accH[rt][u][g] = {0.f, 0.f, 0.f, 0.f};
      }

  const uint16_t* ap0 = aggio + (size_t)r0 * 128 + quad * 8;
  const uint16_t* ap1 = aggio + (size_t)r1 * 128 + quad * 8;
  const uint16_t* xp0 = xb + (size_t)r0 * 128 + quad * 8;
  const uint16_t* xp1 = xb + (size_t)r1 * 128 + quad * 8;
#pragma unroll
  for (int kc = 0; kc < 4; kc++) {
    v8s a0 = ok0 ? *reinterpret_cast<const v8s*>(ap0 + kc * 32) : z8;
    v8s a1 = ok1 ? *reinterpret_cast<const v8s*>(ap1 + kc * 32) : z8;
    v8s x0 = ok0 ? *reinterpret_cast<const v8s*>(xp0 + kc * 32) : z8;
    v8s x1 = ok1 ? *reinterpret_cast<const v8s*>(xp1 + kc * 32) : z8;
    const uint16_t* wp = Wrp + (size_t)((kc * 4 + wave) * 12) * 512 + (size_t)lane * 8;
#pragma unroll
    for (int u = 0; u < 2; u++) {
#pragma unroll
      for (int g = 0; g < 3; g++) {
        v8s bi = *reinterpret_cast<const v8s*>(wp + (u * 6 + g) * 512);
        v8s bh = *reinterpret_cast<const v8s*>(wp + (u * 6 + 3 + g) * 512);
        accI[0][u][g] = __builtin_amdgcn_mfma_f32_16x16x32_bf16(a0, bi, accI[0][u][g], 0, 0, 0);
        accI[1][u][g] = __builtin_amdgcn_mfma_f32_16x16x32_bf16(a1, bi, accI[1][u][g], 0, 0, 0);
        accH[0][u][g] = __builtin_amdgcn_mfma_f32_16x16x32_bf16(x0, bh, accH[0][u][g], 0, 0, 0);
        accH[1][u][g] = __builtin_amdgcn_mfma_f32_16x16x32_bf16(x1, bh, accH[1][u][g], 0, 0, 0);
      }
    }
  }

  // gates epilogue -> LDS
#pragma unroll
  for (int rt = 0; rt < 2; rt++) {
#pragma unroll
    for (int u = 0; u < 2; u++) {
      int col = wave * 32 + u * 16 + n0;
      float bir = bih[col], biz = bih[128 + col], bin = bih[256 + col];
      float bhr = bhh[col], bhz = bhh[128 + col], bhn = bhh[256 + col];
#pragma unroll
      for (int r = 0; r < 4; r++) {
        int rl = rt * 16 + quad * 4 + r;
        int row = m0 + rl;
        float ir = accI[rt][u][0][r] + bir;
        float iz = accI[rt][u][1][r] + biz;
        float in_ = accI[rt][u][2][r] + bin;
        float hr = accH[rt][u][0][r] + bhr;
        float hz = accH[rt][u][1][r] + bhz;
        float hn = accH[rt][u][2][r] + bhn;
        float rr = sigmoidf_(ir + hr);
        float zz = sigmoidf_(iz + hz);
        float nn = tanhf(fmaf(rr, hn, in_));
        float xv = (row < n) ? bf2f(xb[(size_t)row * 128 + col]) : 0.f;
        hl[rl][col] = f2b(fmaf(zz, xv - nn, nn));
      }
    }
  }
  __syncthreads();

  // phase 2: hid = relu(h @ ginw1^T + gb1); wave covers cols [32w, 32w+32)
  v4f acc2[2][2];
#pragma unroll
  for (int rt = 0; rt < 2; rt++)
#pragma unroll
    for (int u = 0; u < 2; u++) acc2[rt][u] = {0.f, 0.f, 0.f, 0.f};

#pragma unroll
  for (int kc = 0; kc < 4; kc++) {
    v8s a0 = *reinterpret_cast<const v8s*>(&hl[n0][kc * 32 + quad * 8]);
    v8s a1 = *reinterpret_cast<const v8s*>(&hl[16 + n0][kc * 32 + quad * 8]);
#pragma unroll
    for (int u = 0; u < 2; u++) {
      int t = wave * 2 + u;
      v8s bf = *reinterpret_cast<const v8s*>(G1rp + (size_t)kc * 4096 + (size_t)t * 512 + (size_t)lane * 8);
      acc2[0][u] = __builtin_amdgcn_mfma_f32_16x16x32_bf16(a0, bf, acc2[0][u], 0, 0, 0);
      acc2[1][u] = __builtin_amdgcn_mfma_f32_16x16x32_bf16(a1, bf, acc2[1][u], 0, 0, 0);
    }
  }

#pragma unroll
  for (int rt = 0; rt < 2; rt++) {
#pragma unroll
    for (int u = 0; u < 2; u++) {
      int col = wave * 32 + u * 16 + n0;
      float b = gb1[col];
#pragma unroll
      for (int r = 0; r < 4; r++) {
        int row = m0 + rt * 16 + quad * 4 + r;
        if (row < n)
          hidout[(size_t)row * 128 + col] = f2b(fmaxf(acc2[rt][u][r] + b, 0.f));
      }
    }
  }
}

// ---------------------------------------------------------------------------
extern "C" void kernel_launch(void* const* d_in, const int* in_sizes, int n_in,
                              void* d_out, int out_size, void* d_ws, size_t ws_size,
                              hipStream_t stream) {
  const int N = in_sizes[0] / 128;   // 100000
  const int E = in_sizes[2];         // 1600000
  const int N8 = N * 8;              // sub-segmented CSR entries

  static const int wn[18] = {16384, 128, 49152, 384, 49152, 384,
                             147456, 147456, 1152, 1152, 49152, 384,
                             256, 2, 768, 6, 2688, 21};
  CvtDesc cd;
  int off = 0;
  for (int i = 0; i < 18; i++) {
    cd.src[i] = d_in[3 + i];
    cd.off[i] = off;
    off += wn[i];
  }
  cd.off[18] = off;
  const int wtotal = off;  // 466077

  // ---- workspace bump allocator (~78 MB) ----
  char* p = (char*)d_ws;
  size_t used = 0;
  auto alloc = [&](size_t bytes) -> char* {
    char* r = p;
    size_t b = (bytes + 255) & ~(size_t)255;
    p += b;
    used += b;
    return r;
  };
  int*      flag    = (int*)alloc(256);
  float*    wbase   = (float*)alloc((size_t)wtotal * 4);
  uint16_t* wb16    = (uint16_t*)alloc((size_t)wtotal * 2);
  uint16_t* mmrp    = (uint16_t*)alloc((size_t)10 * 16384 * 2);      // repacked mm W
  uint16_t* grurp   = (uint16_t*)alloc((size_t)3 * 192 * 512 * 2);   // repacked gru W
  uint16_t* xb      = (uint16_t*)alloc((size_t)N * 128 * 2);
  uint16_t* aggb    = (uint16_t*)alloc((size_t)N * 128 * 2);         // feat / agg / hid
  int*      deg2    = (int*)alloc((size_t)N8 * 4);
  int*      rowptr2 = (int*)alloc((size_t)(N8 + 1) * 4);
  int*      cursor2 = (int*)alloc((size_t)N8 * 4);
  uint2*    epack   = (uint2*)alloc((size_t)E * 8);
  int*      bsum    = (int*)alloc(4096);

  // FLOAT32 output layout (elements): log0|log1|log2|soft0|soft1|soft2
  float* out = (float*)d_out;
  float* outlog[3]  = {out, out + 2 * (size_t)N, out + 8 * (size_t)N};
  float* outsoft[3] = {out + 29 * (size_t)N, out + 31 * (size_t)N, out + 37 * (size_t)N};

  if (used > ws_size) {
    k_zero_f<<<(out_size + 255) / 256, 256, 0, stream>>>(out, out_size);
    return;
  }

  float* b1f   = wbase + cd.off[1];
  float* ginb1 = wbase + cd.off[3];
  float* ginb2 = wbase + cd.off[5];
  float* bih   = wbase + cd.off[8];
  float* bhh   = wbase + cd.off[9];
  float* hb1   = wbase + cd.off[11];
  float* hw2_0 = wbase + cd.off[12];
  float* hb2_0 = wbase + cd.off[13];
  float* hw2_1 = wbase + cd.off[14];
  float* hb2_1 = wbase + cd.off[15];
  float* hw2_2 = wbase + cd.off[16];
  float* hb2_2 = wbase + cd.off[17];

  uint16_t* w1b   = wb16 + cd.off[0];
  uint16_t* ginw1b= wb16 + cd.off[2];
  uint16_t* ginw2b= wb16 + cd.off[4];
  uint16_t* wihb  = wb16 + cd.off[6];
  uint16_t* whhb  = wb16 + cd.off[7];
  uint16_t* hw1b  = wb16 + cd.off[10];

  uint16_t* w1rp    = mmrp;
  uint16_t* ginw1rp = mmrp + (size_t)1 * 16384;
  uint16_t* ginw2rp = mmrp + (size_t)4 * 16384;
  uint16_t* hw1rp   = mmrp + (size_t)7 * 16384;

  const int* dst = (const int*)d_in[1];       // edge_index[0]
  const int* src = (const int*)d_in[1] + E;   // edge_index[1]

  // ---- dtype probe + conversions + repack ----
  k_detect<<<1, 64, 0, stream>>>((const uint32_t*)d_in[0], flag);
  k_cvtw<<<(wtotal + 255) / 256, 256, 0, stream>>>(cd, wbase, wb16, flag, wtotal);
  k_cvt_feat<<<((size_t)N * 128 + 255) / 256, 256, 0, stream>>>(d_in[0], aggb,
                                                                N * 128, flag);
  k_pack_mm<<<(1 * 2048 + 255) / 256, 256, 0, stream>>>(w1b, w1rp, 1);
  k_pack_mm<<<(3 * 2048 + 255) / 256, 256, 0, stream>>>(ginw1b, ginw1rp, 3);
  k_pack_mm<<<(3 * 2048 + 255) / 256, 256, 0, stream>>>(ginw2b, ginw2rp, 3);
  k_pack_mm<<<(3 * 2048 + 255) / 256, 256, 0, stream>>>(hw1b, hw1rp, 3);
  k_pack_gru<<<(3 * 192 * 64 + 255) / 256, 256, 0, stream>>>(wihb, whhb, grurp, 3);

  // ---- CSR build (per-vXCD sub-segmented) ----
  k_zero_i<<<(N8 + 255) / 256, 256, 0, stream>>>(deg2, N8);
  k_hist<<<(E + 255) / 256, 256, 0, stream>>>(dst, deg2, E);
  int nb = (N8 + 1023) / 1024;   // 782 <= 1024 (scan2 capacity)
  k_scan1<<<nb, 256, 0, stream>>>(deg2, bsum, N8);
  k_scan2<<<1, 256, 0, stream>>>(bsum, nb, rowptr2, N8);
  k_scan3<<<nb, 256, 0, stream>>>(deg2, bsum, rowptr2, cursor2, N8);
  k_scatter<<<(E + 255) / 256, 256, 0, stream>>>(dst, src, d_in[2], cursor2,
                                                 epack, flag, E);

  int mmrb = (N + 127) / 128;  // 128 rows/block (4 waves x 32)
  int grub = (N + 31) / 32;    // 32 rows/block
  int spb  = (N + 3) / 4;

  // mlp1: xb = relu(features(aggb) @ w1^T + b1)
  k_mm<1><<<mmrb, 256, 0, stream>>>(aggb, w1rp, b1f, xb, N);

  for (int i = 0; i < 3; i++) {
    // aggb = spmm(xb)
    k_spmm<<<spb, 256, 0, stream>>>(xb, rowptr2, epack, aggb, N);
    // aggb = relu(GRU(aggb, xb) @ ginw1^T + ginb1)   [fused, h stays in LDS]
    k_grug<<<grub, 256, 0, stream>>>(aggb, xb, grurp + (size_t)i * 192 * 512,
                                     ginw1rp + (size_t)i * 16384,
                                     bih + i * 384, bhh + i * 384,
                                     ginb1 + i * 128, aggb, N);
    // xb = norm(relu(aggb @ ginw2^T + ginb2))
    k_mm<2><<<mmrb, 256, 0, stream>>>(aggb, ginw2rp + (size_t)i * 16384,
                                      ginb2 + i * 128, xb, N);
    // fused: hid = relu(xb @ hw1^T + hb1) in LDS -> head + softmax, f32 out
    if (i == 0)
      k_mmh<2><<<mmrb, 256, 0, stream>>>(xb, hw1rp, hb1, hw2_0, hb2_0,
                                         outlog[0], outsoft[0], N);
    else if (i == 1)
      k_mmh<6><<<mmrb, 256, 0, stream>>>(xb, hw1rp + (size_t)16384, hb1 + 128,
                                         hw2_1, hb2_1, outlog[1], outsoft[1], N);
    else
      k_mmh<21><<<mmrb, 256, 0, stream>>>(xb, hw1rp + (size_t)2 * 16384, hb1 + 256,
                                          hw2_2, hb2_2, outlog[2], outsoft[2], N);
  }
}